// Round 1
// baseline (1016.723 us; speedup 1.0000x reference)
//
#include <hip/hip_runtime.h>
#include <hip/hip_bf16.h>

#define N_CAT   100000
#define N_USERS 50000
#define N_REL   32
#define D       64
#define NEDGE   1600000
#define NNZ     1000000

// ---------------------------------------------------------------------------
// ws layout (floats):
//   norm2   : N_CAT*N_REL          (12.8 MB)
//   attw    : NEDGE                ( 6.4 MB)   att, then reused as exp-weight
//   grp_max : N_CAT  (float bits as int)
//   grp_sum : N_CAT
// total 5.0M floats = 20 MB
// ---------------------------------------------------------------------------

// norm2[n][r] = sum_d (cat[n][d]*W[r][d])^2
__global__ void norm2_kernel(const float* __restrict__ cat,
                             const float* __restrict__ W,
                             float* __restrict__ norm2) {
    int gid = blockIdx.x * blockDim.x + threadIdx.x;
    if (gid >= N_CAT * N_REL) return;
    int node = gid >> 5;          // 32 consecutive threads share a node row (broadcast)
    int rel  = gid & 31;
    const float4* c = (const float4*)(cat + (size_t)node * D);
    const float4* w = (const float4*)(W + (size_t)rel * D);
    float s = 0.f;
#pragma unroll
    for (int i = 0; i < 16; ++i) {
        float4 a = c[i], b = w[i];
        float p0 = a.x * b.x, p1 = a.y * b.y, p2 = a.z * b.z, p3 = a.w * b.w;
        s += p0 * p0 + p1 * p1 + p2 * p2 + p3 * p3;
    }
    norm2[gid] = s;
}

// att[e] = norm2[head][rel] * norm2[tail][rel]; segment max via int atomicMax
// (valid because att >= 0: non-negative float bits compare like signed ints)
__global__ void att_max_kernel(const int* __restrict__ head,
                               const int* __restrict__ tail,
                               const int* __restrict__ etype,
                               const float* __restrict__ norm2,
                               float* __restrict__ attw,
                               int* __restrict__ grp_max) {
    int e = blockIdx.x * blockDim.x + threadIdx.x;
    if (e >= NEDGE) return;
    int h = head[e], t = tail[e], r = etype[e] - 1;
    float a = norm2[h * N_REL + r] * norm2[t * N_REL + r];
    attw[e] = a;
    atomicMax(&grp_max[h], __float_as_int(a));
}

// attw[e] = exp(att - max); grp_sum[h] += attw[e]
__global__ void exp_sum_kernel(const int* __restrict__ head,
                               float* __restrict__ attw,
                               const int* __restrict__ grp_max,
                               float* __restrict__ grp_sum) {
    int e = blockIdx.x * blockDim.x + threadIdx.x;
    if (e >= NEDGE) return;
    int h = head[e];
    float m  = __int_as_float(grp_max[h]);
    float ew = __expf(attw[e] - m);
    attw[e] = ew;
    atomicAdd(&grp_sum[h], ew);
}

// one wave per edge, lane = d: cat_agg[head][d] += w * cat[tail][d] * W[rel][d]
__global__ void cat_agg_kernel(const int* __restrict__ head,
                               const int* __restrict__ tail,
                               const int* __restrict__ etype,
                               const float* __restrict__ attw,
                               const float* __restrict__ grp_sum,
                               const float* __restrict__ cat,
                               const float* __restrict__ W,
                               float* __restrict__ cat_agg) {
    int gid  = blockIdx.x * blockDim.x + threadIdx.x;
    int e    = gid >> 6;
    int lane = gid & 63;
    if (e >= NEDGE) return;
    int h = head[e], t = tail[e], r = etype[e] - 1;
    float wgt = attw[e] / grp_sum[h];
    float v = wgt * cat[(size_t)t * D + lane] * W[r * D + lane];
    atomicAdd(&cat_agg[(size_t)h * D + lane], v);
}

// one wave per nnz: uagg[row][d] += val * cat[col][d]
__global__ void spmm_kernel(const int* __restrict__ rows,
                            const int* __restrict__ cols,
                            const float* __restrict__ vals,
                            const float* __restrict__ cat,
                            float* __restrict__ uagg) {
    int gid  = blockIdx.x * blockDim.x + threadIdx.x;
    int n    = gid >> 6;
    int lane = gid & 63;
    if (n >= NNZ) return;
    int rr = rows[n], cc = cols[n];
    float v = vals[n];
    atomicAdd(&uagg[(size_t)rr * D + lane], v * cat[(size_t)cc * D + lane]);
}

// one wave per user: score = softmax(u @ W^T) [32]; uagg *= (1 + score @ W)
__global__ void final_kernel(const float* __restrict__ uemb,
                             const float* __restrict__ W,
                             float* __restrict__ uagg) {
    __shared__ float s_user[4][D];
    __shared__ float s_score[4][N_REL];
    int wv   = threadIdx.x >> 6;
    int lane = threadIdx.x & 63;
    int u = blockIdx.x * 4 + wv;          // N_USERS % 4 == 0, no guard needed

    s_user[wv][lane] = uemb[(size_t)u * D + lane];
    __syncthreads();

    if (lane < N_REL) {
        float dot = 0.f;
#pragma unroll
        for (int d = 0; d < D; ++d) dot += s_user[wv][d] * W[lane * D + d];
        float m = dot;
#pragma unroll
        for (int off = 16; off > 0; off >>= 1) m = fmaxf(m, __shfl_xor(m, off));
        float ex = __expf(dot - m);
        float ssum = ex;
#pragma unroll
        for (int off = 16; off > 0; off >>= 1) ssum += __shfl_xor(ssum, off);
        s_score[wv][lane] = ex / ssum;
    }
    __syncthreads();

    float proj = 0.f;
#pragma unroll
    for (int r = 0; r < N_REL; ++r) proj += s_score[wv][r] * W[r * D + lane];

    size_t idx = (size_t)u * D + lane;
    float a = uagg[idx];
    uagg[idx] = a * (1.f + proj);
}

extern "C" void kernel_launch(void* const* d_in, const int* in_sizes, int n_in,
                              void* d_out, int out_size, void* d_ws, size_t ws_size,
                              hipStream_t stream) {
    const float* cat   = (const float*)d_in[0];
    const float* uemb  = (const float*)d_in[1];
    const int*   eidx  = (const int*)d_in[2];
    const int*   etype = (const int*)d_in[3];
    const int*   imr   = (const int*)d_in[4];
    const int*   imc   = (const int*)d_in[5];
    const float* imv   = (const float*)d_in[6];
    const float* W     = (const float*)d_in[7];
    const int* head = eidx;
    const int* tail = eidx + NEDGE;

    float* out     = (float*)d_out;
    float* cat_agg = out;                         // [N_CAT, D]
    float* uagg    = out + (size_t)N_CAT * D;     // [N_USERS, D]

    float* norm2   = (float*)d_ws;
    float* attw    = norm2 + (size_t)N_CAT * N_REL;
    int*   grp_max = (int*)(attw + NEDGE);
    float* grp_sum = (float*)(grp_max + N_CAT);

    // zero accumulators (d_out re-poisoned to 0xAA before every timed launch)
    hipMemsetAsync(d_out, 0, (size_t)out_size * sizeof(float), stream);
    hipMemsetAsync(grp_max, 0, 2 * (size_t)N_CAT * sizeof(float), stream);

    norm2_kernel  <<<(N_CAT * N_REL + 255) / 256, 256, 0, stream>>>(cat, W, norm2);
    att_max_kernel<<<(NEDGE + 255) / 256,          256, 0, stream>>>(head, tail, etype, norm2, attw, grp_max);
    exp_sum_kernel<<<(NEDGE + 255) / 256,          256, 0, stream>>>(head, attw, grp_max, grp_sum);
    cat_agg_kernel<<<(NEDGE * 64) / 256,           256, 0, stream>>>(head, tail, etype, attw, grp_sum, cat, W, cat_agg);
    spmm_kernel   <<<(NNZ * 64) / 256,             256, 0, stream>>>(imr, imc, imv, cat, uagg);
    final_kernel  <<<N_USERS / 4,                  256, 0, stream>>>(uemb, W, uagg);
}

// Round 2
// 807.478 us; speedup vs baseline: 1.2591x; 1.2591x over previous
//
#include <hip/hip_runtime.h>
#include <hip/hip_bf16.h>
#include <float.h>

#define N_CAT   100000
#define N_USERS 50000
#define N_REL   32
#define D       64
#define NEDGE   1600000
#define NNZ     1000000
#define NBINS   (N_CAT + N_USERS)          // 150000 concatenated histogram bins
#define SCAN_B  ((NBINS + 255) / 256)      // 586 scan blocks

// ---------------------------------------------------------------------------
// ws layout:
//   norm2     : N_CAT*N_REL floats (12.8 MB)
//   cnt       : NBINS ints   (0.6 MB)   histogram
//   offs      : NBINS ints   (0.6 MB)   exclusive scan (cat bins, then usr bins offset by +E)
//   cursor    : NBINS ints   (0.6 MB)   scatter cursors (copy of offs)
//   bsum      : SCAN_B ints
//   sorted_ta : NEDGE int2   (12.8 MB)  {(tail<<5)|rel, att_bits} sorted by head
//   sorted_cv : NNZ  int2    ( 8.0 MB)  {col, val_bits} sorted by row
// total ~35.5 MB
// ---------------------------------------------------------------------------

__global__ void norm2_kernel(const float* __restrict__ cat,
                             const float* __restrict__ W,
                             float* __restrict__ norm2) {
    int gid = blockIdx.x * blockDim.x + threadIdx.x;
    if (gid >= N_CAT * N_REL) return;
    int node = gid >> 5;
    int rel  = gid & 31;
    const float4* c = (const float4*)(cat + (size_t)node * D);
    const float4* w = (const float4*)(W + (size_t)rel * D);
    float s = 0.f;
#pragma unroll
    for (int i = 0; i < 16; ++i) {
        float4 a = c[i], b = w[i];
        float p0 = a.x * b.x, p1 = a.y * b.y, p2 = a.z * b.z, p3 = a.w * b.w;
        s += p0 * p0 + p1 * p1 + p2 * p2 + p3 * p3;
    }
    norm2[gid] = s;
}

// histogram: edges by head into bins [0,N_CAT), nnz by row into bins [N_CAT,NBINS)
__global__ void hist_kernel(const int* __restrict__ head,
                            const int* __restrict__ imr,
                            int* __restrict__ cnt) {
    int gid = blockIdx.x * blockDim.x + threadIdx.x;
    if (gid < NEDGE) {
        atomicAdd(&cnt[head[gid]], 1);
    } else if (gid < NEDGE + NNZ) {
        atomicAdd(&cnt[N_CAT + imr[gid - NEDGE]], 1);
    }
}

// two-level exclusive scan over cnt[NBINS]
__global__ void scan1_kernel(const int* __restrict__ cnt,
                             int* __restrict__ offs,
                             int* __restrict__ bsum) {
    __shared__ int s[256];
    int t = threadIdx.x;
    int i = blockIdx.x * 256 + t;
    int v = (i < NBINS) ? cnt[i] : 0;
    s[t] = v;
    __syncthreads();
#pragma unroll
    for (int off = 1; off < 256; off <<= 1) {
        int x = (t >= off) ? s[t - off] : 0;
        __syncthreads();
        s[t] += x;
        __syncthreads();
    }
    if (i < NBINS) offs[i] = s[t] - v;       // exclusive
    if (t == 255) bsum[blockIdx.x] = s[t];   // block total
}

__global__ void scan2_kernel(int* __restrict__ bsum) {
    __shared__ int s[1024];
    int t = threadIdx.x;
    int v = (t < SCAN_B) ? bsum[t] : 0;
    s[t] = v;
    __syncthreads();
#pragma unroll
    for (int off = 1; off < 1024; off <<= 1) {
        int x = (t >= off) ? s[t - off] : 0;
        __syncthreads();
        s[t] += x;
        __syncthreads();
    }
    if (t < SCAN_B) bsum[t] = s[t] - v;      // exclusive
}

__global__ void scan3_kernel(int* __restrict__ offs,
                             const int* __restrict__ bsum,
                             int* __restrict__ cursor) {
    int i = blockIdx.x * 256 + threadIdx.x;
    if (i >= NBINS) return;
    int o = offs[i] + bsum[i >> 8];
    offs[i]   = o;
    cursor[i] = o;
}

// scatter edges (with att computed here) and nnz into sorted bins
__global__ void scatter_kernel(const int* __restrict__ head,
                               const int* __restrict__ tail,
                               const int* __restrict__ etype,
                               const float* __restrict__ norm2,
                               const int* __restrict__ imr,
                               const int* __restrict__ imc,
                               const float* __restrict__ imv,
                               int* __restrict__ cursor,
                               int2* __restrict__ sorted_ta,
                               int2* __restrict__ sorted_cv) {
    int gid = blockIdx.x * blockDim.x + threadIdx.x;
    if (gid < NEDGE) {
        int h = head[gid], t = tail[gid], r = etype[gid] - 1;
        float att = norm2[h * N_REL + r] * norm2[t * N_REL + r];
        int pos = atomicAdd(&cursor[h], 1);
        sorted_ta[pos] = make_int2((t << 5) | r, __float_as_int(att));
    } else if (gid < NEDGE + NNZ) {
        int n = gid - NEDGE;
        int rr = imr[n];
        int pos = atomicAdd(&cursor[N_CAT + rr], 1) - NEDGE;
        sorted_cv[pos] = make_int2(imc[n], __float_as_int(imv[n]));
    }
}

// one wave per head: softmax over its edges + weighted gather-reduce, plain store
__global__ void cat_agg_sorted_kernel(const int* __restrict__ offs,
                                      const int2* __restrict__ sorted_ta,
                                      const float* __restrict__ cat,
                                      const float* __restrict__ W,
                                      float* __restrict__ cat_agg) {
    int wv   = threadIdx.x >> 6;
    int lane = threadIdx.x & 63;
    int h = blockIdx.x * 4 + wv;              // 100000 % 4 == 0
    int start = offs[h];
    int end   = offs[h + 1];                  // offs[N_CAT] == NEDGE (usr segment start)
    int deg   = end - start;

    // pass 1: max of att
    float m = -FLT_MAX;
    for (int j = lane; j < deg; j += 64)
        m = fmaxf(m, __int_as_float(sorted_ta[start + j].y));
#pragma unroll
    for (int off = 32; off > 0; off >>= 1) m = fmaxf(m, __shfl_xor(m, off));

    // pass 2: sum of exp
    float s = 0.f;
    for (int j = lane; j < deg; j += 64)
        s += __expf(__int_as_float(sorted_ta[start + j].y) - m);
#pragma unroll
    for (int off = 32; off > 0; off >>= 1) s += __shfl_xor(s, off);
    float inv = (deg > 0) ? 1.f / s : 0.f;

    // pass 3: weighted accumulate (lane = d)
    float acc = 0.f;
    for (int j = 0; j < deg; ++j) {
        int2 ta = sorted_ta[start + j];       // lane-uniform -> broadcast
        float w = __expf(__int_as_float(ta.y) - m) * inv;
        int t = ta.x >> 5, r = ta.x & 31;
        acc += w * cat[(size_t)t * D + lane] * W[r * D + lane];
    }
    cat_agg[(size_t)h * D + lane] = acc;
}

// one wave per user: SpMM row + relation-softmax gating, plain store
__global__ void spmm_user_kernel(const int* __restrict__ offs,
                                 const int2* __restrict__ sorted_cv,
                                 const float* __restrict__ cat,
                                 const float* __restrict__ uemb,
                                 const float* __restrict__ W,
                                 float* __restrict__ uagg) {
    __shared__ float s_user[4][D];
    __shared__ float s_score[4][N_REL];
    int wv   = threadIdx.x >> 6;
    int lane = threadIdx.x & 63;
    int u = blockIdx.x * 4 + wv;              // 50000 % 4 == 0
    int start = offs[N_CAT + u] - NEDGE;
    int end   = (u == N_USERS - 1) ? NNZ : offs[N_CAT + u + 1] - NEDGE;

    float acc = 0.f;
    for (int j = start; j < end; ++j) {
        int2 cv = sorted_cv[j];               // lane-uniform -> broadcast
        acc += __int_as_float(cv.y) * cat[(size_t)cv.x * D + lane];
    }

    s_user[wv][lane] = uemb[(size_t)u * D + lane];
    __syncthreads();

    if (lane < N_REL) {
        float dot = 0.f;
#pragma unroll
        for (int d = 0; d < D; ++d) dot += s_user[wv][d] * W[lane * D + d];
        float mm = dot;
#pragma unroll
        for (int off = 16; off > 0; off >>= 1) mm = fmaxf(mm, __shfl_xor(mm, off));
        float ex = __expf(dot - mm);
        float ssum = ex;
#pragma unroll
        for (int off = 16; off > 0; off >>= 1) ssum += __shfl_xor(ssum, off);
        s_score[wv][lane] = ex / ssum;
    }
    __syncthreads();

    float proj = 0.f;
#pragma unroll
    for (int r = 0; r < N_REL; ++r) proj += s_score[wv][r] * W[r * D + lane];

    uagg[(size_t)u * D + lane] = acc * (1.f + proj);
}

extern "C" void kernel_launch(void* const* d_in, const int* in_sizes, int n_in,
                              void* d_out, int out_size, void* d_ws, size_t ws_size,
                              hipStream_t stream) {
    const float* cat   = (const float*)d_in[0];
    const float* uemb  = (const float*)d_in[1];
    const int*   eidx  = (const int*)d_in[2];
    const int*   etype = (const int*)d_in[3];
    const int*   imr   = (const int*)d_in[4];
    const int*   imc   = (const int*)d_in[5];
    const float* imv   = (const float*)d_in[6];
    const float* W     = (const float*)d_in[7];
    const int* head = eidx;
    const int* tail = eidx + NEDGE;

    float* out     = (float*)d_out;
    float* cat_agg = out;                         // [N_CAT, D]
    float* uagg    = out + (size_t)N_CAT * D;     // [N_USERS, D]

    float* norm2   = (float*)d_ws;
    int*   cnt     = (int*)(norm2 + (size_t)N_CAT * N_REL);
    int*   offs    = cnt + NBINS;
    int*   cursor  = offs + NBINS;
    int*   bsum    = cursor + NBINS;
    int2*  sorted_ta = (int2*)(bsum + ((SCAN_B + 1) & ~1));  // 8B aligned
    int2*  sorted_cv = sorted_ta + NEDGE;

    hipMemsetAsync(cnt, 0, (size_t)NBINS * sizeof(int), stream);

    norm2_kernel<<<(N_CAT * N_REL + 255) / 256, 256, 0, stream>>>(cat, W, norm2);
    hist_kernel<<<(NEDGE + NNZ + 255) / 256, 256, 0, stream>>>(head, imr, cnt);
    scan1_kernel<<<SCAN_B, 256, 0, stream>>>(cnt, offs, bsum);
    scan2_kernel<<<1, 1024, 0, stream>>>(bsum);
    scan3_kernel<<<SCAN_B, 256, 0, stream>>>(offs, bsum, cursor);
    scatter_kernel<<<(NEDGE + NNZ + 255) / 256, 256, 0, stream>>>(
        head, tail, etype, norm2, imr, imc, imv, cursor, sorted_ta, sorted_cv);
    cat_agg_sorted_kernel<<<N_CAT / 4, 256, 0, stream>>>(offs, sorted_ta, cat, W, cat_agg);
    spmm_user_kernel<<<N_USERS / 4, 256, 0, stream>>>(offs, sorted_cv, cat, uemb, W, uagg);
}

// Round 3
// 644.489 us; speedup vs baseline: 1.5776x; 1.2529x over previous
//
#include <hip/hip_runtime.h>
#include <hip/hip_bf16.h>
#include <float.h>

#define N_CAT   100000
#define N_USERS 50000
#define N_REL   32
#define D       64
#define NEDGE   1600000
#define NNZ     1000000
#define NBINS   (N_CAT + N_USERS)          // 150000 concatenated histogram bins
#define SCAN_B  ((NBINS + 255) / 256)      // 586 scan blocks

__global__ void norm2_kernel(const float* __restrict__ cat,
                             const float* __restrict__ W,
                             float* __restrict__ norm2) {
    int gid = blockIdx.x * blockDim.x + threadIdx.x;
    if (gid >= N_CAT * N_REL) return;
    int node = gid >> 5;
    int rel  = gid & 31;
    const float4* c = (const float4*)(cat + (size_t)node * D);
    const float4* w = (const float4*)(W + (size_t)rel * D);
    float s = 0.f;
#pragma unroll
    for (int i = 0; i < 16; ++i) {
        float4 a = c[i], b = w[i];
        float p0 = a.x * b.x, p1 = a.y * b.y, p2 = a.z * b.z, p3 = a.w * b.w;
        s += p0 * p0 + p1 * p1 + p2 * p2 + p3 * p3;
    }
    norm2[gid] = s;
}

__global__ void hist_kernel(const int* __restrict__ head,
                            const int* __restrict__ imr,
                            int* __restrict__ cnt) {
    int gid = blockIdx.x * blockDim.x + threadIdx.x;
    if (gid < NEDGE) {
        atomicAdd(&cnt[head[gid]], 1);
    } else if (gid < NEDGE + NNZ) {
        atomicAdd(&cnt[N_CAT + imr[gid - NEDGE]], 1);
    }
}

__global__ void scan1_kernel(const int* __restrict__ cnt,
                             int* __restrict__ offs,
                             int* __restrict__ bsum) {
    __shared__ int s[256];
    int t = threadIdx.x;
    int i = blockIdx.x * 256 + t;
    int v = (i < NBINS) ? cnt[i] : 0;
    s[t] = v;
    __syncthreads();
#pragma unroll
    for (int off = 1; off < 256; off <<= 1) {
        int x = (t >= off) ? s[t - off] : 0;
        __syncthreads();
        s[t] += x;
        __syncthreads();
    }
    if (i < NBINS) offs[i] = s[t] - v;
    if (t == 255) bsum[blockIdx.x] = s[t];
}

__global__ void scan2_kernel(int* __restrict__ bsum) {
    __shared__ int s[1024];
    int t = threadIdx.x;
    int v = (t < SCAN_B) ? bsum[t] : 0;
    s[t] = v;
    __syncthreads();
#pragma unroll
    for (int off = 1; off < 1024; off <<= 1) {
        int x = (t >= off) ? s[t - off] : 0;
        __syncthreads();
        s[t] += x;
        __syncthreads();
    }
    if (t < SCAN_B) bsum[t] = s[t] - v;
}

__global__ void scan3_kernel(int* __restrict__ offs,
                             const int* __restrict__ bsum,
                             int* __restrict__ cursor) {
    int i = blockIdx.x * 256 + threadIdx.x;
    if (i >= NBINS) return;
    int o = offs[i] + bsum[i >> 8];
    offs[i]   = o;
    cursor[i] = o;
}

__global__ void scatter_kernel(const int* __restrict__ head,
                               const int* __restrict__ tail,
                               const int* __restrict__ etype,
                               const float* __restrict__ norm2,
                               const int* __restrict__ imr,
                               const int* __restrict__ imc,
                               const float* __restrict__ imv,
                               int* __restrict__ cursor,
                               int2* __restrict__ sorted_ta,
                               int2* __restrict__ sorted_cv) {
    int gid = blockIdx.x * blockDim.x + threadIdx.x;
    if (gid < NEDGE) {
        int h = head[gid], t = tail[gid], r = etype[gid] - 1;
        float att = norm2[h * N_REL + r] * norm2[t * N_REL + r];
        int pos = atomicAdd(&cursor[h], 1);
        sorted_ta[pos] = make_int2((t << 5) | r, __float_as_int(att));
    } else if (gid < NEDGE + NNZ) {
        int n = gid - NEDGE;
        int rr = imr[n];
        int pos = atomicAdd(&cursor[N_CAT + rr], 1) - NEDGE;
        sorted_cv[pos] = make_int2(imc[n], __float_as_int(imv[n]));
    }
}

// one wave per head: softmax + gather-reduce with lane-parallel preload and
// 4-way independent gathers in flight
__global__ void cat_agg_sorted_kernel(const int* __restrict__ offs,
                                      const int2* __restrict__ sorted_ta,
                                      const float* __restrict__ cat,
                                      const float* __restrict__ W,
                                      float* __restrict__ cat_agg) {
    int wv   = threadIdx.x >> 6;
    int lane = threadIdx.x & 63;
    int h = blockIdx.x * 4 + wv;
    int start = offs[h];
    int end   = offs[h + 1];                  // offs[N_CAT] == NEDGE
    int deg   = end - start;

    // pass 1: segment max (lane-parallel)
    float m = -FLT_MAX;
    for (int j = lane; j < deg; j += 64)
        m = fmaxf(m, __int_as_float(sorted_ta[start + j].y));
#pragma unroll
    for (int off = 32; off > 0; off >>= 1) m = fmaxf(m, __shfl_xor(m, off));

    // pass 2: exp-sum (lane-parallel)
    float ssum = 0.f;
    for (int j = lane; j < deg; j += 64)
        ssum += __expf(__int_as_float(sorted_ta[start + j].y) - m);
#pragma unroll
    for (int off = 32; off > 0; off >>= 1) ssum += __shfl_xor(ssum, off);
    float inv = (deg > 0) ? 1.f / ssum : 0.f;

    // pass 3: chunked lane-parallel preload, shuffle-broadcast, 4 gathers in flight
    float a0 = 0.f, a1 = 0.f, a2 = 0.f, a3 = 0.f;
    for (int j0 = 0; j0 < deg; j0 += 64) {
        int n = min(64, deg - j0);
        int   my_tr = 0;
        float my_w  = 0.f;
        if (lane < n) {
            int2 ta = sorted_ta[start + j0 + lane];
            my_tr = ta.x;
            my_w  = __expf(__int_as_float(ta.y) - m) * inv;   // softmax weight, once
        }
        int j = 0;
        for (; j + 4 <= n; j += 4) {
            int   tr0 = __shfl(my_tr, j + 0), tr1 = __shfl(my_tr, j + 1);
            int   tr2 = __shfl(my_tr, j + 2), tr3 = __shfl(my_tr, j + 3);
            float w0  = __shfl(my_w,  j + 0), w1  = __shfl(my_w,  j + 1);
            float w2  = __shfl(my_w,  j + 2), w3  = __shfl(my_w,  j + 3);
            float c0 = cat[(size_t)(tr0 >> 5) * D + lane];
            float c1 = cat[(size_t)(tr1 >> 5) * D + lane];
            float c2 = cat[(size_t)(tr2 >> 5) * D + lane];
            float c3 = cat[(size_t)(tr3 >> 5) * D + lane];
            float e0 = W[(tr0 & 31) * D + lane];
            float e1 = W[(tr1 & 31) * D + lane];
            float e2 = W[(tr2 & 31) * D + lane];
            float e3 = W[(tr3 & 31) * D + lane];
            a0 += w0 * c0 * e0;
            a1 += w1 * c1 * e1;
            a2 += w2 * c2 * e2;
            a3 += w3 * c3 * e3;
        }
        for (; j < n; ++j) {
            int   tr = __shfl(my_tr, j);
            float w  = __shfl(my_w,  j);
            a0 += w * cat[(size_t)(tr >> 5) * D + lane] * W[(tr & 31) * D + lane];
        }
    }
    cat_agg[(size_t)h * D + lane] = (a0 + a1) + (a2 + a3);
}

// one wave per user: SpMM row (4 gathers in flight) + relation-softmax gating
__global__ void spmm_user_kernel(const int* __restrict__ offs,
                                 const int2* __restrict__ sorted_cv,
                                 const float* __restrict__ cat,
                                 const float* __restrict__ uemb,
                                 const float* __restrict__ W,
                                 float* __restrict__ uagg) {
    __shared__ float s_user[4][D];
    __shared__ float s_score[4][N_REL];
    int wv   = threadIdx.x >> 6;
    int lane = threadIdx.x & 63;
    int u = blockIdx.x * 4 + wv;
    int start = offs[N_CAT + u] - NEDGE;
    int end   = (u == N_USERS - 1) ? NNZ : offs[N_CAT + u + 1] - NEDGE;
    int deg   = end - start;

    float a0 = 0.f, a1 = 0.f, a2 = 0.f, a3 = 0.f;
    for (int j0 = 0; j0 < deg; j0 += 64) {
        int n = min(64, deg - j0);
        int   my_c = 0;
        float my_v = 0.f;
        if (lane < n) {
            int2 cv = sorted_cv[start + j0 + lane];
            my_c = cv.x;
            my_v = __int_as_float(cv.y);
        }
        int j = 0;
        for (; j + 4 <= n; j += 4) {
            int   c0 = __shfl(my_c, j + 0), c1 = __shfl(my_c, j + 1);
            int   c2 = __shfl(my_c, j + 2), c3 = __shfl(my_c, j + 3);
            float v0 = __shfl(my_v, j + 0), v1 = __shfl(my_v, j + 1);
            float v2 = __shfl(my_v, j + 2), v3 = __shfl(my_v, j + 3);
            a0 += v0 * cat[(size_t)c0 * D + lane];
            a1 += v1 * cat[(size_t)c1 * D + lane];
            a2 += v2 * cat[(size_t)c2 * D + lane];
            a3 += v3 * cat[(size_t)c3 * D + lane];
        }
        for (; j < n; ++j) {
            int   c = __shfl(my_c, j);
            float v = __shfl(my_v, j);
            a0 += v * cat[(size_t)c * D + lane];
        }
    }
    float acc = (a0 + a1) + (a2 + a3);

    s_user[wv][lane] = uemb[(size_t)u * D + lane];
    __syncthreads();

    if (lane < N_REL) {
        float dot = 0.f;
#pragma unroll
        for (int d = 0; d < D; ++d) dot += s_user[wv][d] * W[lane * D + d];
        float mm = dot;
#pragma unroll
        for (int off = 16; off > 0; off >>= 1) mm = fmaxf(mm, __shfl_xor(mm, off));
        float ex = __expf(dot - mm);
        float sm = ex;
#pragma unroll
        for (int off = 16; off > 0; off >>= 1) sm += __shfl_xor(sm, off);
        s_score[wv][lane] = ex / sm;
    }
    __syncthreads();

    float proj = 0.f;
#pragma unroll
    for (int r = 0; r < N_REL; ++r) proj += s_score[wv][r] * W[r * D + lane];

    uagg[(size_t)u * D + lane] = acc * (1.f + proj);
}

extern "C" void kernel_launch(void* const* d_in, const int* in_sizes, int n_in,
                              void* d_out, int out_size, void* d_ws, size_t ws_size,
                              hipStream_t stream) {
    const float* cat   = (const float*)d_in[0];
    const float* uemb  = (const float*)d_in[1];
    const int*   eidx  = (const int*)d_in[2];
    const int*   etype = (const int*)d_in[3];
    const int*   imr   = (const int*)d_in[4];
    const int*   imc   = (const int*)d_in[5];
    const float* imv   = (const float*)d_in[6];
    const float* W     = (const float*)d_in[7];
    const int* head = eidx;
    const int* tail = eidx + NEDGE;

    float* out     = (float*)d_out;
    float* cat_agg = out;                         // [N_CAT, D]
    float* uagg    = out + (size_t)N_CAT * D;     // [N_USERS, D]

    float* norm2   = (float*)d_ws;
    int*   cnt     = (int*)(norm2 + (size_t)N_CAT * N_REL);
    int*   offs    = cnt + NBINS;
    int*   cursor  = offs + NBINS;
    int*   bsum    = cursor + NBINS;
    int2*  sorted_ta = (int2*)(bsum + ((SCAN_B + 1) & ~1));
    int2*  sorted_cv = sorted_ta + NEDGE;

    hipMemsetAsync(cnt, 0, (size_t)NBINS * sizeof(int), stream);

    norm2_kernel<<<(N_CAT * N_REL + 255) / 256, 256, 0, stream>>>(cat, W, norm2);
    hist_kernel<<<(NEDGE + NNZ + 255) / 256, 256, 0, stream>>>(head, imr, cnt);
    scan1_kernel<<<SCAN_B, 256, 0, stream>>>(cnt, offs, bsum);
    scan2_kernel<<<1, 1024, 0, stream>>>(bsum);
    scan3_kernel<<<SCAN_B, 256, 0, stream>>>(offs, bsum, cursor);
    scatter_kernel<<<(NEDGE + NNZ + 255) / 256, 256, 0, stream>>>(
        head, tail, etype, norm2, imr, imc, imv, cursor, sorted_ta, sorted_cv);
    cat_agg_sorted_kernel<<<N_CAT / 4, 256, 0, stream>>>(offs, sorted_ta, cat, W, cat_agg);
    spmm_user_kernel<<<N_USERS / 4, 256, 0, stream>>>(offs, sorted_cv, cat, uemb, W, uagg);
}